// Round 1
// baseline (16104.507 us; speedup 1.0000x reference)
//
#include <hip/hip_runtime.h>
#include <stdint.h>

// 2-layer LSTM persistent pipeline for MI355X.
// 4 stages x 32 batch-groups = 128 blocks x 640 threads (10 waves).
// Weights live in registers as MFMA B-fragments; stages stream activations
// through ring buffers in d_ws using agent-scope atomics (XCD-safe).

#define TT 1024
#define BATCH 512
#define II 80
#define HH 160

constexpr int BB    = 16;            // batch rows per group
constexpr int NGRP  = BATCH / BB;    // 32
constexpr int NTHR  = 640;           // 10 waves
constexpr int NWAVE = 10;
constexpr int DEPTH = 4;             // ring depth (power of 2)
constexpr int HP    = 168;           // LDS row stride in shorts (160 + 8 pad)

typedef __attribute__((ext_vector_type(8))) short s8b;   // 8 x bf16 bits
typedef __attribute__((ext_vector_type(4))) float f4;

// workspace layout (bytes)
constexpr size_t OFF_FLAGS = 0;                                   // int prog[NGRP][4]
constexpr size_t OFF_G0    = 4096;
constexpr size_t SLOT_F32  = (size_t)NTHR * 64;                   // 40960 B: 16 fp32/thread
constexpr size_t OFF_P     = OFF_G0 + (size_t)NGRP * DEPTH * SLOT_F32;
constexpr size_t OFF_H0    = OFF_P  + (size_t)NGRP * DEPTH * SLOT_F32;
constexpr size_t SLOT_H0   = (size_t)NTHR * 8;                    // 5120 B
// total ~10.7 MB of d_ws

__device__ __forceinline__ short f2bf(float x){
  uint32_t u = __builtin_bit_cast(uint32_t, x);
  u = (u + 0x7FFFu + ((u >> 16) & 1u)) >> 16;   // RNE
  return (short)u;
}
__device__ __forceinline__ float u64lo(uint64_t v){ return __builtin_bit_cast(float,(uint32_t)v); }
__device__ __forceinline__ float u64hi(uint64_t v){ return __builtin_bit_cast(float,(uint32_t)(v>>32)); }
__device__ __forceinline__ uint64_t packf2(float a, float b){
  return (uint64_t)__builtin_bit_cast(uint32_t,a) | ((uint64_t)__builtin_bit_cast(uint32_t,b) << 32);
}
__device__ __forceinline__ float sigf (float x){ return 1.f/(1.f+__expf(-x)); }
__device__ __forceinline__ float tanh_(float x){ return 1.f - 2.f/(__expf(2.f*x)+1.f); }

__device__ __forceinline__ f4 mfma_bf16(s8b a, s8b b, f4 c){
  return __builtin_amdgcn_mfma_f32_16x16x32_bf16(a, b, c, 0, 0, 0);
}

// agent-scope (device) coherent accesses: bypass non-coherent per-XCD caches
__device__ __forceinline__ void st64(uint64_t* p, uint64_t v){
  __hip_atomic_store(p, v, __ATOMIC_RELAXED, __HIP_MEMORY_SCOPE_AGENT);
}
__device__ __forceinline__ uint64_t ld64(const uint64_t* p){
  return __hip_atomic_load(p, __ATOMIC_RELAXED, __HIP_MEMORY_SCOPE_AGENT);
}

// wave-cooperative poll: lane 0 loads flag, broadcasts; shadow is monotone
__device__ __forceinline__ void poll_ge(int* p, int& shadow, int target, int lane){
  while (shadow < target){
    int v = 0;
    if (lane == 0) v = __hip_atomic_load(p, __ATOMIC_ACQUIRE, __HIP_MEMORY_SCOPE_AGENT);
    shadow = __shfl(v, 0, 64);
    if (shadow < target) __builtin_amdgcn_s_sleep(1);
  }
}

// load register-resident MFMA B-fragments of W [640 x KDIM] (gate-major rows).
// B[k][n] = W[n][k]; lane: n = n0 + (l&15), k = kt*32 + (l>>4)*8 + j
template<int KT, int KDIM>
__device__ __forceinline__ void load_wfrags(const float* W, int w, int lq, int lr,
                                            s8b (&bw)[KT][4]){
  #pragma unroll
  for (int kt = 0; kt < KT; ++kt){
    #pragma unroll
    for (int g = 0; g < 4; ++g){
      const int row = g*HH + 16*w + lr;
      const int k0  = kt*32 + lq*8;
      s8b f;
      #pragma unroll
      for (int j = 0; j < 8; ++j) f[j] = 0;
      if (k0 < KDIM){
        const float* p = W + (size_t)row*KDIM + k0;
        #pragma unroll
        for (int j = 0; j < 8; ++j) f[j] = f2bf(p[j]);
      }
      bw[kt][g] = f;
    }
  }
}

__global__ __launch_bounds__(NTHR, 3)   // 3 waves/EU min -> VGPR cap ~170 (block must fit 3,3,2,2)
void lstm_pipe(const float* __restrict__ x,
               const float* __restrict__ Wih0, const float* __restrict__ Whh0,
               const float* __restrict__ bih0, const float* __restrict__ bhh0,
               const float* __restrict__ Wih1, const float* __restrict__ Whh1,
               const float* __restrict__ bih1, const float* __restrict__ bhh1,
               const float* __restrict__ Wout, const float* __restrict__ bout,
               float* __restrict__ out, char* __restrict__ ws)
{
  const int tid = threadIdx.x;
  const int w   = tid >> 6;      // wave 0..9 : owns H-cols [16w,16w+16)
  const int l   = tid & 63;
  const int lq  = l >> 4;        // quad
  const int lr  = l & 15;
  const int stage = blockIdx.x & 3;
  const int gid   = blockIdx.x >> 2;
  const int b0    = gid * BB;

  int* prog        = (int*)(ws + OFF_FLAGS) + gid*4;
  uint64_t* g0ring = (uint64_t*)(ws + OFF_G0 + (size_t)gid*DEPTH*SLOT_F32);
  uint64_t* pring  = (uint64_t*)(ws + OFF_P  + (size_t)gid*DEPTH*SLOT_F32);
  uint64_t* h0ring = (uint64_t*)(ws + OFF_H0 + (size_t)gid*DEPTH*SLOT_H0);

  __shared__ __align__(16) short hsh[2][16*HP];     // h in A-layout, double-buffered
  __shared__ __align__(16) float ypart[2][16][16];  // [buf][wave][row]

  if (stage == 0){
    // ---- S0a: G0 = x @ W_ih0^T + (b_ih0 + b_hh0), K padded 80->96 ----
    s8b bw[3][4];
    load_wfrags<3, II>(Wih0, w, lq, lr, bw);
    float bias[4];
    #pragma unroll
    for (int g = 0; g < 4; ++g) bias[g] = bih0[g*HH + 16*w + lr] + bhh0[g*HH + 16*w + lr];
    int shc = 0;
    for (int t = 0; t < TT; ++t){
      s8b a[3];
      #pragma unroll
      for (int kt = 0; kt < 3; ++kt){
        const int k0 = kt*32 + lq*8;
        s8b f;
        #pragma unroll
        for (int j = 0; j < 8; ++j) f[j] = 0;
        if (k0 < II){
          const float* p = x + ((size_t)(b0+lr)*TT + t)*II + k0;
          #pragma unroll
          for (int j = 0; j < 8; ++j) f[j] = f2bf(p[j]);
        }
        a[kt] = f;
      }
      f4 acc[4];
      #pragma unroll
      for (int g = 0; g < 4; ++g){
        acc[g][0]=bias[g]; acc[g][1]=bias[g]; acc[g][2]=bias[g]; acc[g][3]=bias[g];
      }
      #pragma unroll
      for (int kt = 0; kt < 3; ++kt)
        #pragma unroll
        for (int g = 0; g < 4; ++g) acc[g] = mfma_bf16(a[kt], bw[kt][g], acc[g]);
      if (t >= DEPTH) poll_ge(&prog[1], shc, t - DEPTH + 1, l);   // slot reuse gate
      uint64_t* slot = g0ring + (size_t)(t & (DEPTH-1))*(SLOT_F32/8) + (size_t)tid*8;
      #pragma unroll
      for (int g = 0; g < 4; ++g){
        st64(slot + g*2 + 0, packf2(acc[g][0], acc[g][1]));
        st64(slot + g*2 + 1, packf2(acc[g][2], acc[g][3]));
      }
      __syncthreads();  // drains vmcnt for all threads before flag
      if (tid == 0) __hip_atomic_store(&prog[0], t+1, __ATOMIC_RELEASE, __HIP_MEMORY_SCOPE_AGENT);
    }
  }
  else if (stage == 1){
    // ---- S0b: gates0 = G0 + h0 @ W_hh0^T ; cell0 ; emit h0 ----
    s8b bw[5][4];
    load_wfrags<5, HH>(Whh0, w, lq, lr, bw);
    float c[4] = {0.f,0.f,0.f,0.f};
    for (int i = tid; i < 2*16*HP; i += NTHR) ((short*)hsh)[i] = 0;
    __syncthreads();
    int shp = 0, shc = 0;
    for (int t = 0; t < TT; ++t){
      poll_ge(&prog[0], shp, t+1, l);
      const uint64_t* gslot = g0ring + (size_t)(t & (DEPTH-1))*(SLOT_F32/8) + (size_t)tid*8;
      uint64_t gin[8];
      #pragma unroll
      for (int q = 0; q < 8; ++q) gin[q] = ld64(gslot + q);   // in flight over MFMA
      s8b a[5];
      #pragma unroll
      for (int kt = 0; kt < 5; ++kt)
        a[kt] = *(const s8b*)&hsh[(t+1)&1][lr*HP + kt*32 + lq*8];
      f4 acc[4];
      #pragma unroll
      for (int g = 0; g < 4; ++g){ acc[g][0]=0.f; acc[g][1]=0.f; acc[g][2]=0.f; acc[g][3]=0.f; }
      #pragma unroll
      for (int kt = 0; kt < 5; ++kt)
        #pragma unroll
        for (int g = 0; g < 4; ++g) acc[g] = mfma_bf16(a[kt], bw[kt][g], acc[g]);
      short* hb = hsh[t&1];
      uint64_t hpk = 0;
      #pragma unroll
      for (int r = 0; r < 4; ++r){
        float gv[4];
        #pragma unroll
        for (int g = 0; g < 4; ++g){
          uint64_t u = gin[g*2 + (r>>1)];
          gv[g] = acc[g][r] + ((r&1) ? u64hi(u) : u64lo(u));
        }
        float cn = sigf(gv[1])*c[r] + sigf(gv[0])*tanh_(gv[2]);
        c[r] = cn;
        float h = sigf(gv[3])*tanh_(cn);
        short h16 = f2bf(h);
        hb[(lq*4+r)*HP + 16*w + lr] = h16;                      // own recurrence
        hpk |= (uint64_t)(uint16_t)h16 << (16*r);
      }
      if (t >= DEPTH) poll_ge(&prog[2], shc, t - DEPTH + 1, l);
      st64(h0ring + (size_t)(t & (DEPTH-1))*(SLOT_H0/8) + tid, hpk);  // C-frag dump
      __syncthreads();
      if (tid == 0) __hip_atomic_store(&prog[1], t+1, __ATOMIC_RELEASE, __HIP_MEMORY_SCOPE_AGENT);
    }
  }
  else if (stage == 2){
    // ---- S1: P = h0 @ W_ih1^T + (b_ih1 + b_hh1) ----
    s8b bw[5][4];
    load_wfrags<5, HH>(Wih1, w, lq, lr, bw);
    float bias[4];
    #pragma unroll
    for (int g = 0; g < 4; ++g) bias[g] = bih1[g*HH + 16*w + lr] + bhh1[g*HH + 16*w + lr];
    int shp = 0, shc = 0;
    for (int t = 0; t < TT; ++t){
      poll_ge(&prog[1], shp, t+1, l);
      uint64_t hu = ld64(h0ring + (size_t)(t & (DEPTH-1))*(SLOT_H0/8) + tid);
      #pragma unroll
      for (int r = 0; r < 4; ++r)   // scatter C-layout -> A-layout in LDS
        hsh[0][(lq*4+r)*HP + 16*w + lr] = (short)(uint16_t)(hu >> (16*r));
      __syncthreads();
      s8b a[5];
      #pragma unroll
      for (int kt = 0; kt < 5; ++kt)
        a[kt] = *(const s8b*)&hsh[0][lr*HP + kt*32 + lq*8];
      f4 acc[4];
      #pragma unroll
      for (int g = 0; g < 4; ++g){
        acc[g][0]=bias[g]; acc[g][1]=bias[g]; acc[g][2]=bias[g]; acc[g][3]=bias[g];
      }
      #pragma unroll
      for (int kt = 0; kt < 5; ++kt)
        #pragma unroll
        for (int g = 0; g < 4; ++g) acc[g] = mfma_bf16(a[kt], bw[kt][g], acc[g]);
      if (t >= DEPTH) poll_ge(&prog[3], shc, t - DEPTH + 1, l);
      uint64_t* slot = pring + (size_t)(t & (DEPTH-1))*(SLOT_F32/8) + (size_t)tid*8;
      #pragma unroll
      for (int g = 0; g < 4; ++g){
        st64(slot + g*2 + 0, packf2(acc[g][0], acc[g][1]));
        st64(slot + g*2 + 1, packf2(acc[g][2], acc[g][3]));
      }
      __syncthreads();
      if (tid == 0) __hip_atomic_store(&prog[2], t+1, __ATOMIC_RELEASE, __HIP_MEMORY_SCOPE_AGENT);
    }
  }
  else {
    // ---- S2: gates1 = P + h1 @ W_hh1^T ; cell1 ; y = relu(h1.Wout + b) ----
    s8b bw[5][4];
    load_wfrags<5, HH>(Whh1, w, lq, lr, bw);
    float c[4] = {0.f,0.f,0.f,0.f};
    const float wcol = Wout[16*w + lr];
    const float bo   = bout[0];
    for (int i = tid; i < 2*16*HP; i += NTHR) ((short*)hsh)[i] = 0;
    __syncthreads();
    int shp = 0;
    for (int t = 0; t < TT; ++t){
      poll_ge(&prog[2], shp, t+1, l);
      const uint64_t* pslot = pring + (size_t)(t & (DEPTH-1))*(SLOT_F32/8) + (size_t)tid*8;
      uint64_t pin[8];
      #pragma unroll
      for (int q = 0; q < 8; ++q) pin[q] = ld64(pslot + q);
      s8b a[5];
      #pragma unroll
      for (int kt = 0; kt < 5; ++kt)
        a[kt] = *(const s8b*)&hsh[(t+1)&1][lr*HP + kt*32 + lq*8];
      f4 acc[4];
      #pragma unroll
      for (int g = 0; g < 4; ++g){ acc[g][0]=0.f; acc[g][1]=0.f; acc[g][2]=0.f; acc[g][3]=0.f; }
      #pragma unroll
      for (int kt = 0; kt < 5; ++kt)
        #pragma unroll
        for (int g = 0; g < 4; ++g) acc[g] = mfma_bf16(a[kt], bw[kt][g], acc[g]);
      short* hb = hsh[t&1];
      float yp[4];
      #pragma unroll
      for (int r = 0; r < 4; ++r){
        float gv[4];
        #pragma unroll
        for (int g = 0; g < 4; ++g){
          uint64_t u = pin[g*2 + (r>>1)];
          gv[g] = acc[g][r] + ((r&1) ? u64hi(u) : u64lo(u));
        }
        float cn = sigf(gv[1])*c[r] + sigf(gv[0])*tanh_(gv[2]);
        c[r] = cn;
        float h = sigf(gv[3])*tanh_(cn);
        hb[(lq*4+r)*HP + 16*w + lr] = f2bf(h);
        yp[r] = h * wcol;   // fp32 h for the head
      }
      #pragma unroll
      for (int off = 1; off < 16; off <<= 1){
        #pragma unroll
        for (int r = 0; r < 4; ++r) yp[r] += __shfl_xor(yp[r], off, 64);
      }
      if (lr == 0)
        *(float4*)&ypart[t&1][w][lq*4] = make_float4(yp[0], yp[1], yp[2], yp[3]);
      __syncthreads();
      if (w == 0 && l < 16){
        float s = bo;
        #pragma unroll
        for (int ww = 0; ww < NWAVE; ++ww) s += ypart[t&1][ww][l];
        out[(size_t)(b0+l)*TT + t] = fmaxf(s, 0.f);
      }
      if (tid == 0) __hip_atomic_store(&prog[3], t+1, __ATOMIC_RELEASE, __HIP_MEMORY_SCOPE_AGENT);
    }
  }
}

extern "C" void kernel_launch(void* const* d_in, const int* in_sizes, int n_in,
                              void* d_out, int out_size, void* d_ws, size_t ws_size,
                              hipStream_t stream)
{
  (void)in_sizes; (void)n_in; (void)out_size; (void)ws_size;
  // zero the pipeline progress flags (d_ws is poisoned 0xAA before each launch)
  hipMemsetAsync(d_ws, 0, 4096, stream);
  lstm_pipe<<<dim3(NGRP*4), dim3(NTHR), 0, stream>>>(
      (const float*)d_in[0],
      (const float*)d_in[1], (const float*)d_in[2],
      (const float*)d_in[3], (const float*)d_in[4],
      (const float*)d_in[5], (const float*)d_in[6],
      (const float*)d_in[7], (const float*)d_in[8],
      (const float*)d_in[9], (const float*)d_in[10],
      (float*)d_out, (char*)d_ws);
}

// Round 3
// 8739.265 us; speedup vs baseline: 1.8428x; 1.8428x over previous
//
#include <hip/hip_runtime.h>
#include <stdint.h>

// 2-layer LSTM (B=512,T=1024,I=80,H=160) on MI355X.
// 2 CUs per model replica: block A = layer0 (Wih0+Whh0 = 307KB regs),
// block B = layer1 + head (Wih1+Whh1 = 410KB regs). 32 groups x 2 = 64 blocks
// x 512 threads (8 waves, __launch_bounds__(512,2): 256 VGPR cap, 1 block/CU).
// Cross-block traffic: h0(t) only, 5KB/step, in MFMA A-frag layout through a
// DEPTH=16 ring (deep ring => producer runs ahead, HBM latency off the
// critical path — round 1's DEPTH=4 serialized on the round trip).
// Gate-interleaved cols: phys col P = 4*hc + g; tile ct covers hc 4ct..4ct+3,
// so gate gather is an intra-quad 4x4 DPP transpose (qtrans).

#define TT 1024
#define BATCH 512
#define II 80
#define HH 160

constexpr int BB    = 16;
constexpr int NGRP  = BATCH / BB;   // 32
constexpr int NW    = 8;
constexpr int NTHR  = NW * 64;      // 512
constexpr int NTILE = 5;            // 40 col-tiles / 8 waves
constexpr int DEPTH = 16;           // ring depth (power of 2)
constexpr int HP    = 168;          // LDS h row stride (shorts)

typedef __attribute__((ext_vector_type(8))) short s8b;
typedef __attribute__((ext_vector_type(4))) float f4;
typedef __attribute__((ext_vector_type(2))) unsigned long long u64x2;

constexpr size_t OFF_RING = 4096;                 // flags in [0,4096)
constexpr size_t SLOT     = 5120;                 // 16x160 bf16, [kt][lane][16B]
constexpr size_t RING_STRIDE = (size_t)DEPTH * SLOT;

__device__ __forceinline__ short f2bf(float x){
  uint32_t u = __builtin_bit_cast(uint32_t, x);
  u = (u + 0x7FFFu + ((u >> 16) & 1u)) >> 16;     // RNE
  return (short)u;
}
__device__ __forceinline__ float sigf(float x){ return 1.f/(1.f+__expf(-x)); }
__device__ __forceinline__ float tanh_(float x){ return 1.f - 2.f/(__expf(2.f*x)+1.f); }

__device__ __forceinline__ f4 mfma16(s8b a, s8b b, f4 c){
  return __builtin_amdgcn_mfma_f32_16x16x32_bf16(a, b, c, 0, 0, 0);
}

template<int CTRL>
__device__ __forceinline__ float qperm(float v){
  return __builtin_bit_cast(float,
    __builtin_amdgcn_mov_dpp(__builtin_bit_cast(int, v), CTRL, 0xf, 0xf, true));
}
// intra-quad 4x4 transpose: acc[r] = gate q of row lq*4+r -> gv[g] = gate g of row lq*4+q
__device__ __forceinline__ void qtrans(f4 acc, int q, float gv[4]){
  float a0=acc[0], a1=acc[1], a2=acc[2], a3=acc[3];
  float s0 = q==0?a0 : q==1?a1 : q==2?a2 : a3;
  float s1 = q==0?a3 : q==1?a0 : q==2?a1 : a2;
  float s2 = q==0?a2 : q==1?a3 : q==2?a0 : a1;
  float s3 = q==0?a1 : q==1?a2 : q==2?a3 : a0;
  float r0 = s0;
  float r1 = qperm<0x39>(s1);   // sel [1,2,3,0]
  float r2 = qperm<0x4E>(s2);   // sel [2,3,0,1]
  float r3 = qperm<0x93>(s3);   // sel [3,0,1,2]
  gv[0] = q==0?r0 : q==1?r3 : q==2?r2 : r1;
  gv[1] = q==0?r1 : q==1?r0 : q==2?r3 : r2;
  gv[2] = q==0?r2 : q==1?r1 : q==2?r0 : r3;
  gv[3] = q==0?r3 : q==1?r2 : q==2?r1 : r0;
}

__device__ __forceinline__ s8b pack8(float4 a, float4 b){
  s8b r;
  r[0]=f2bf(a.x); r[1]=f2bf(a.y); r[2]=f2bf(a.z); r[3]=f2bf(a.w);
  r[4]=f2bf(b.x); r[5]=f2bf(b.y); r[6]=f2bf(b.z); r[7]=f2bf(b.w);
  return r;
}
__device__ __forceinline__ float4 ld4(const float* p){ return *(const float4*)p; }
__device__ __forceinline__ s8b wfrag(const float* p){ return pack8(ld4(p), ld4(p+4)); }

__device__ __forceinline__ void st64(unsigned long long* p, unsigned long long v){
  __hip_atomic_store(p, v, __ATOMIC_RELAXED, __HIP_MEMORY_SCOPE_AGENT);
}
__device__ __forceinline__ unsigned long long ld64(const unsigned long long* p){
  return __hip_atomic_load(p, __ATOMIC_RELAXED, __HIP_MEMORY_SCOPE_AGENT);
}
__device__ __forceinline__ void poll_ge(int* p, int& shadow, int target, int lane){
  while (shadow < target){
    int v = 0;
    if (lane == 0) v = __hip_atomic_load(p, __ATOMIC_ACQUIRE, __HIP_MEMORY_SCOPE_AGENT);
    shadow = __shfl(v, 0, 64);
    if (shadow < target) __builtin_amdgcn_s_sleep(1);
  }
}

__global__ __launch_bounds__(NTHR, 2)
void lstm2(const float* __restrict__ x,
           const float* __restrict__ Wih0, const float* __restrict__ Whh0,
           const float* __restrict__ bih0, const float* __restrict__ bhh0,
           const float* __restrict__ Wih1, const float* __restrict__ Whh1,
           const float* __restrict__ bih1, const float* __restrict__ bhh1,
           const float* __restrict__ Wout, const float* __restrict__ bout,
           float* __restrict__ out, char* __restrict__ ws)
{
  const int tid = threadIdx.x;
  const int w   = tid >> 6;
  const int l   = tid & 63;
  const int lq  = l >> 4;
  const int lr  = l & 15;
  const int q   = l & 3;
  const int h2  = (l >> 2) & 3;
  const int stage = blockIdx.x >> 5;      // pair (g, g+32): same XCD under %8 round-robin
  const int gid   = blockIdx.x & 31;
  const int b0    = gid * BB;

  int* prog = (int*)ws + gid*2;           // [0]=A progress, [1]=B progress
  unsigned long long* ring =
      (unsigned long long*)(ws + OFF_RING + (size_t)gid * RING_STRIDE);

  __shared__ __align__(16) short hsh[16 * HP];
  __shared__ float biassh[40 * 16];
  __shared__ float woutsh[HH];
  __shared__ float ypart[NW][16];
  const s8b zf = {};

  if (stage == 0){
    // ================= stage A: layer 0 =================
    s8b Wi[NTILE][3], Wh[NTILE][5];
    float bias0[NTILE];
    #pragma unroll
    for (int s = 0; s < NTILE; ++s){
      const int ct = w + 8*s;
      const int wrow = q*HH + 4*ct + h2;
      bias0[s] = bih0[wrow] + bhh0[wrow];
      #pragma unroll
      for (int kt = 0; kt < 3; ++kt){
        const int k0 = kt*32 + lq*8;
        Wi[s][kt] = (k0 + 8 <= II) ? wfrag(Wih0 + (size_t)wrow*II + k0) : zf;
      }
      #pragma unroll
      for (int kt = 0; kt < 5; ++kt)
        Wh[s][kt] = wfrag(Whh0 + (size_t)wrow*HH + kt*32 + lq*8);
    }
    s8b xa[3], h0a[5];
    #pragma unroll
    for (int kt = 0; kt < 5; ++kt) h0a[kt] = zf;
    float c0[NTILE] = {0.f,0.f,0.f,0.f,0.f};

    const float* xb = x + (size_t)(b0 + lr) * TT * II;
    {
      float4 a0 = ld4(xb + lq*8),      a1 = ld4(xb + lq*8 + 4);
      float4 a2 = ld4(xb + 32 + lq*8), a3 = ld4(xb + 32 + lq*8 + 4);
      const float* x2 = (lq < 2) ? xb + 64 + lq*8 : xb;   // predicate addr: no OOB
      float4 a4 = ld4(x2), a5 = ld4(x2 + 4);
      xa[0] = pack8(a0,a1); xa[1] = pack8(a2,a3);
      xa[2] = (lq < 2) ? pack8(a4,a5) : zf;
    }

    int credB = 0;
    for (int t = 0; t < TT; ++t){
      // prefetch x(t+1)
      const int tn = (t+1 < TT) ? t+1 : t;
      const float* xr = xb + (size_t)tn * II;
      float4 n0 = ld4(xr + lq*8),      n1 = ld4(xr + lq*8 + 4);
      float4 n2 = ld4(xr + 32 + lq*8), n3 = ld4(xr + 32 + lq*8 + 4);
      const float* x2 = (lq < 2) ? xr + 64 + lq*8 : xr;
      float4 n4 = ld4(x2), n5 = ld4(x2 + 4);

      if (t >= DEPTH) poll_ge(&prog[1], credB, t - DEPTH + 1, l);  // slot credit

      #pragma unroll
      for (int s = 0; s < NTILE; ++s){
        f4 acc = {bias0[s], bias0[s], bias0[s], bias0[s]};
        acc = mfma16(xa[0], Wi[s][0], acc);
        acc = mfma16(xa[1], Wi[s][1], acc);
        acc = mfma16(xa[2], Wi[s][2], acc);
        #pragma unroll
        for (int kt = 0; kt < 5; ++kt) acc = mfma16(h0a[kt], Wh[s][kt], acc);
        float gv[4]; qtrans(acc, q, gv);
        const float cn = sigf(gv[1])*c0[s] + sigf(gv[0])*tanh_(gv[2]);
        c0[s] = cn;
        const float h = sigf(gv[3])*tanh_(cn);
        hsh[(lq*4 + q)*HP + 4*(w + 8*s) + h2] = f2bf(h);
      }
      __syncthreads();                                   // h0(t) visible in LDS
      #pragma unroll
      for (int kt = 0; kt < 5; ++kt)
        h0a[kt] = *(const s8b*)&hsh[lr*HP + kt*32 + lq*8];
      if (w < 5){                                        // ship frag (kt=w, lane l)
        unsigned long long* dst = ring + (size_t)(t & (DEPTH-1))*640 + w*128 + l*2;
        u64x2 v = __builtin_bit_cast(u64x2, h0a[w]);
        st64(dst, v.x); st64(dst + 1, v.y);
      }
      __syncthreads();                                   // vmcnt drained before flag
      if (tid == 0)
        __hip_atomic_store(&prog[0], t+1, __ATOMIC_RELEASE, __HIP_MEMORY_SCOPE_AGENT);
      xa[0] = pack8(n0,n1); xa[1] = pack8(n2,n3);
      xa[2] = (lq < 2) ? pack8(n4,n5) : zf;
    }
  }
  else {
    // ================= stage B: layer 1 + head =================
    for (int i = tid; i < 640; i += NTHR){
      const int ct = i >> 4, r = i & 15;
      const int row = (r&3)*HH + 4*ct + (r>>2);
      biassh[i] = bih1[row] + bhh1[row];
    }
    for (int i = tid; i < HH; i += NTHR) woutsh[i] = Wout[i];
    s8b Wi[NTILE][5], Wh[NTILE][5];
    #pragma unroll
    for (int s = 0; s < NTILE; ++s){
      const int ct = w + 8*s;
      const int wrow = q*HH + 4*ct + h2;
      #pragma unroll
      for (int kt = 0; kt < 5; ++kt){
        Wi[s][kt] = wfrag(Wih1 + (size_t)wrow*HH + kt*32 + lq*8);
        Wh[s][kt] = wfrag(Whh1 + (size_t)wrow*HH + kt*32 + lq*8);
      }
    }
    const float bo = bout[0];
    s8b h1a[5];
    #pragma unroll
    for (int kt = 0; kt < 5; ++kt) h1a[kt] = zf;
    float c1[NTILE] = {0.f,0.f,0.f,0.f,0.f};
    __syncthreads();

    int credA = 0;
    for (int t = 0; t < TT; ++t){
      poll_ge(&prog[0], credA, t+1, l);
      // issue h0 frag loads; cover latency with the Whh1 (register) MFMAs
      const unsigned long long* src = ring + (size_t)(t & (DEPTH-1))*640 + l*2;
      unsigned long long hl[5][2];
      #pragma unroll
      for (int kt = 0; kt < 5; ++kt){
        hl[kt][0] = ld64(src + kt*128);
        hl[kt][1] = ld64(src + kt*128 + 1);
      }
      f4 acc[NTILE];
      #pragma unroll
      for (int s = 0; s < NTILE; ++s){
        const float b = biassh[(w + 8*s)*16 + lr];
        acc[s][0]=b; acc[s][1]=b; acc[s][2]=b; acc[s][3]=b;
        #pragma unroll
        for (int kt = 0; kt < 5; ++kt) acc[s] = mfma16(h1a[kt], Wh[s][kt], acc[s]);
      }
      s8b h0n[5];
      #pragma unroll
      for (int kt = 0; kt < 5; ++kt){
        u64x2 v; v.x = hl[kt][0]; v.y = hl[kt][1];
        h0n[kt] = __builtin_bit_cast(s8b, v);
      }
      #pragma unroll
      for (int s = 0; s < NTILE; ++s)
        #pragma unroll
        for (int kt = 0; kt < 5; ++kt) acc[s] = mfma16(h0n[kt], Wi[s][kt], acc[s]);

      float ysum = 0.f;
      #pragma unroll
      for (int s = 0; s < NTILE; ++s){
        float gv[4]; qtrans(acc[s], q, gv);
        const float cn = sigf(gv[1])*c1[s] + sigf(gv[0])*tanh_(gv[2]);
        c1[s] = cn;
        const float h = sigf(gv[3])*tanh_(cn);
        const int hc = 4*(w + 8*s) + h2;
        hsh[(lq*4 + q)*HP + hc] = f2bf(h);
        ysum += h * woutsh[hc];
      }
      ysum += __shfl_xor(ysum, 4, 64);
      ysum += __shfl_xor(ysum, 8, 64);
      if ((l & 12) == 0) ypart[w][lq*4 + q] = ysum;
      __syncthreads();                                   // h1(t) + ypart visible
      if (w == 0 && l < 16){
        float s_ = bo;
        #pragma unroll
        for (int ww = 0; ww < NW; ++ww) s_ += ypart[ww][l];
        out[(size_t)(b0 + l)*TT + t] = fmaxf(s_, 0.f);
      }
      #pragma unroll
      for (int kt = 0; kt < 5; ++kt)
        h1a[kt] = *(const s8b*)&hsh[lr*HP + kt*32 + lq*8];
      __syncthreads();                                   // reads done before next write
      if (tid == 0)
        __hip_atomic_store(&prog[1], t+1, __ATOMIC_RELEASE, __HIP_MEMORY_SCOPE_AGENT);
    }
  }
}

extern "C" void kernel_launch(void* const* d_in, const int* in_sizes, int n_in,
                              void* d_out, int out_size, void* d_ws, size_t ws_size,
                              hipStream_t stream)
{
  (void)in_sizes; (void)n_in; (void)out_size; (void)ws_size;
  hipMemsetAsync(d_ws, 0, 4096, stream);   // progress flags
  lstm2<<<dim3(NGRP*2), dim3(NTHR), 0, stream>>>(
      (const float*)d_in[0],
      (const float*)d_in[1], (const float*)d_in[2],
      (const float*)d_in[3], (const float*)d_in[4],
      (const float*)d_in[5], (const float*)d_in[6],
      (const float*)d_in[7], (const float*)d_in[8],
      (const float*)d_in[9], (const float*)d_in[10],
      (float*)d_out, (char*)d_ws);
}

// Round 5
// 6390.430 us; speedup vs baseline: 2.5201x; 1.3676x over previous
//
#include <hip/hip_runtime.h>
#include <stdint.h>

// 2-layer LSTM (B=512,T=1024,I=80,H=160) on MI355X gfx950.
// 2-stage pipeline, 32 groups x 2 = 64 blocks x 512 thr (8 waves, 2 waves/SIMD
// -> 256 unified regs/wave cap; per-SIMD pool is 512 regs TOTAL — round-3 spilled
// because stage B demanded ~280). Fix: 10 weight frags/wave live in LDS (80KB
// dynamic), keeping reg demand ~225-245/wave.
// Ring: h0 fragments ship as 3xu64 with the timestep tag embedded in EVERY word
// (self-validating): consumer loads speculatively 2 steps ahead, no acquire
// round-trip, producer needs no flag/drain. Only a credit counter B->A every 8
// steps (published post-barrier = free).

#define TT 1024
#define BATCH 512
#define II 80
#define HH 160

constexpr int BB    = 16;
constexpr int NGRP  = BATCH / BB;   // 32
constexpr int NW    = 8;
constexpr int NTHR  = NW * 64;      // 512
constexpr int NTILE = 5;            // 40 col-tiles / 8 waves
constexpr int DEPTH = 32;           // ring depth (power of 2)
constexpr int HP    = 168;          // LDS h row stride (shorts)

typedef __attribute__((ext_vector_type(8))) short s8b;
typedef __attribute__((ext_vector_type(4))) float f4;

// ring: per slot, 5 waves x 64 lanes x 3 u64 = 960 u64 = 7680 B
constexpr int SLOT_U64 = 960;
constexpr size_t OFF_RING = 4096;
constexpr size_t RING_STRIDE = (size_t)DEPTH * SLOT_U64 * 8;   // 245760 B/group

// dynamic LDS layout (bytes)
constexpr int HSH_OFF = 81920;    // h dbuf [2][16*HP] shorts (10752)
constexpr int H0L_OFF = 92672;    // B: h0 dbuf [2][16*HP] shorts (10752)
constexpr int YP_OFF  = 103424;   // B: ypart [2][8][16] float (1024)
constexpr int BS_OFF  = 104448;   // B: bias1 [640] float (2560)
constexpr int WO_OFF  = 107008;   // B: wout [160] float (640)
constexpr int SMEM_SZ = 107648;

__device__ __forceinline__ short f2bf(float x){
  uint32_t u = __builtin_bit_cast(uint32_t, x);
  u = (u + 0x7FFFu + ((u >> 16) & 1u)) >> 16;     // RNE (matches __float2bfloat16_rn)
  return (short)u;
}
__device__ __forceinline__ float sigf(float x){ return 1.f/(1.f+__expf(-x)); }
__device__ __forceinline__ float tanh_(float x){ return 1.f - 2.f/(__expf(2.f*x)+1.f); }

__device__ __forceinline__ f4 mfma16(s8b a, s8b b, f4 c){
  return __builtin_amdgcn_mfma_f32_16x16x32_bf16(a, b, c, 0, 0, 0);
}

template<int CTRL>
__device__ __forceinline__ float qperm(float v){
  return __builtin_bit_cast(float,
    __builtin_amdgcn_mov_dpp(__builtin_bit_cast(int, v), CTRL, 0xf, 0xf, true));
}
// intra-quad 4x4 transpose (proven r3): acc[r]=gate q of row lq*4+r -> gv[g]=gate g of row lq*4+q
__device__ __forceinline__ void qtrans(f4 acc, int q, float gv[4]){
  float a0=acc[0], a1=acc[1], a2=acc[2], a3=acc[3];
  float s0 = q==0?a0 : q==1?a1 : q==2?a2 : a3;
  float s1 = q==0?a3 : q==1?a0 : q==2?a1 : a2;
  float s2 = q==0?a2 : q==1?a3 : q==2?a0 : a1;
  float s3 = q==0?a1 : q==1?a2 : q==2?a3 : a0;
  float r0 = s0;
  float r1 = qperm<0x39>(s1);
  float r2 = qperm<0x4E>(s2);
  float r3 = qperm<0x93>(s3);
  gv[0] = q==0?r0 : q==1?r3 : q==2?r2 : r1;
  gv[1] = q==0?r1 : q==1?r0 : q==2?r3 : r2;
  gv[2] = q==0?r2 : q==1?r1 : q==2?r0 : r3;
  gv[3] = q==0?r3 : q==1?r2 : q==2?r1 : r0;
}

__device__ __forceinline__ s8b pack8(float4 a, float4 b){
  s8b r;
  r[0]=f2bf(a.x); r[1]=f2bf(a.y); r[2]=f2bf(a.z); r[3]=f2bf(a.w);
  r[4]=f2bf(b.x); r[5]=f2bf(b.y); r[6]=f2bf(b.z); r[7]=f2bf(b.w);
  return r;
}
__device__ __forceinline__ float4 ld4(const float* p){ return *(const float4*)p; }
__device__ __forceinline__ s8b wfrag(const float* p){ return pack8(ld4(p), ld4(p+4)); }

__device__ __forceinline__ void st64(unsigned long long* p, unsigned long long v){
  __hip_atomic_store(p, v, __ATOMIC_RELAXED, __HIP_MEMORY_SCOPE_AGENT);
}
__device__ __forceinline__ unsigned long long ld64(const unsigned long long* p){
  return __hip_atomic_load(p, __ATOMIC_RELAXED, __HIP_MEMORY_SCOPE_AGENT);
}
__device__ __forceinline__ void poll_ge(int* p, int& shadow, int target, int lane){
  while (shadow < target){
    int v = 0;
    if (lane == 0) v = __hip_atomic_load(p, __ATOMIC_ACQUIRE, __HIP_MEMORY_SCOPE_AGENT);
    shadow = __shfl(v, 0, 64);
    if (shadow < target) __builtin_amdgcn_s_sleep(2);
  }
}

__global__ __launch_bounds__(NTHR, 1)   // block=512: 2 waves/SIMD -> 256-reg cap
void lstm2(const float* __restrict__ x,
           const float* __restrict__ Wih0, const float* __restrict__ Whh0,
           const float* __restrict__ bih0, const float* __restrict__ bhh0,
           const float* __restrict__ Wih1, const float* __restrict__ Whh1,
           const float* __restrict__ bih1, const float* __restrict__ bhh1,
           const float* __restrict__ Wout, const float* __restrict__ bout,
           float* __restrict__ out, char* __restrict__ ws)
{
  extern __shared__ char smem[];
  const int tid = threadIdx.x;
  const int w   = tid >> 6;
  const int l   = tid & 63;
  const int lq  = l >> 4;
  const int lr  = l & 15;
  const int q   = l & 3;
  const int h2  = (l >> 2) & 3;
  const int stage = blockIdx.x >> 5;
  const int gid   = blockIdx.x & 31;
  const int b0    = gid * BB;

  int* prog = (int*)ws + gid;   // consumer progress (credit to A)
  unsigned long long* ring =
      (unsigned long long*)(ws + OFF_RING + (size_t)gid * RING_STRIDE);

  short* hsh = (short*)(smem + HSH_OFF);                // [2][16*HP]
  const s8b zf = {};

  if (stage == 0){
    // ================= stage A: layer 0 =================
    // Whh0 (25 frags) + Wih0 kt2 (5) in regs; Wih0 kt0,1 (10) in LDS.
    s8b Wh[NTILE][5], Wi2[NTILE];
    float bias0[NTILE];
    #pragma unroll
    for (int s = 0; s < NTILE; ++s){
      const int ct = w + 8*s;
      const int wrow = q*HH + 4*ct + h2;
      bias0[s] = bih0[wrow] + bhh0[wrow];
      #pragma unroll
      for (int kt = 0; kt < 2; ++kt)
        *(s8b*)(smem + ((w*10 + s*2 + kt) << 10) + (l << 4)) =
            wfrag(Wih0 + (size_t)wrow*II + kt*32 + lq*8);
      Wi2[s] = (lq < 2) ? wfrag(Wih0 + (size_t)wrow*II + 64 + lq*8) : zf;
      #pragma unroll
      for (int kt = 0; kt < 5; ++kt)
        Wh[s][kt] = wfrag(Whh0 + (size_t)wrow*HH + kt*32 + lq*8);
    }
    __syncthreads();

    s8b xa[3], h0a[5];
    #pragma unroll
    for (int kt = 0; kt < 5; ++kt) h0a[kt] = zf;
    float c0[NTILE] = {0.f,0.f,0.f,0.f,0.f};

    const float* xb = x + (size_t)(b0 + lr) * TT * II;
    {
      float4 a0 = ld4(xb + lq*8),      a1 = ld4(xb + lq*8 + 4);
      float4 a2 = ld4(xb + 32 + lq*8), a3 = ld4(xb + 32 + lq*8 + 4);
      const float* x2 = (lq < 2) ? xb + 64 + lq*8 : xb;
      float4 a4 = ld4(x2), a5 = ld4(x2 + 4);
      xa[0] = pack8(a0,a1); xa[1] = pack8(a2,a3);
      xa[2] = (lq < 2) ? pack8(a4,a5) : zf;
    }

    int credB = 0;
    for (int t = 0; t < TT; ++t){
      const int tn = (t+1 < TT) ? t+1 : t;             // x(t+1) prefetch
      const float* xr = xb + (size_t)tn * II;
      float4 n0 = ld4(xr + lq*8),      n1 = ld4(xr + lq*8 + 4);
      float4 n2 = ld4(xr + 32 + lq*8), n3 = ld4(xr + 32 + lq*8 + 4);
      const float* x2 = (lq < 2) ? xr + 64 + lq*8 : xr;
      float4 n4 = ld4(x2), n5 = ld4(x2 + 4);

      if (t >= DEPTH && credB < t - DEPTH + 1)
        poll_ge(prog, credB, t - DEPTH + 1, l);        // slot-reuse credit

      short* hb = hsh + (t&1)*16*HP;
      #pragma unroll
      for (int s = 0; s < NTILE; ++s){
        f4 acc = {bias0[s], bias0[s], bias0[s], bias0[s]};
        acc = mfma16(xa[0], *(const s8b*)(smem + ((w*10 + s*2 + 0) << 10) + (l << 4)), acc);
        acc = mfma16(xa[1], *(const s8b*)(smem + ((w*10 + s*2 + 1) << 10) + (l << 4)), acc);
        acc = mfma16(xa[2], Wi2[s], acc);
        #pragma unroll
        for (int kt = 0; kt < 5; ++kt) acc = mfma16(h0a[kt], Wh[s][kt], acc);
        float gv[4]; qtrans(acc, q, gv);
        const float cn = sigf(gv[1])*c0[s] + sigf(gv[0])*tanh_(gv[2]);
        c0[s] = cn;
        const float h = sigf(gv[3])*tanh_(cn);
        hb[(lq*4 + q)*HP + 4*(w + 8*s) + h2] = f2bf(h);
      }
      __syncthreads();                                 // h0(t) visible
      #pragma unroll
      for (int kt = 0; kt < 5; ++kt)
        h0a[kt] = *(const s8b*)&hb[lr*HP + kt*32 + lq*8];
      if (w < 5){                                      // ship frag kt=w, tagged t
        const s8b hf = h0a[w];
        const unsigned long long tg = (unsigned long long)t;
        unsigned long long u0 = (unsigned long long)(unsigned short)hf[0]
                              | ((unsigned long long)(unsigned short)hf[1] << 16)
                              | ((unsigned long long)(unsigned short)hf[2] << 32)
                              | (tg << 48);
        unsigned long long u1 = (unsigned long long)(unsigned short)hf[3]
                              | ((unsigned long long)(unsigned short)hf[4] << 16)
                              | ((unsigned long long)(unsigned short)hf[5] << 32)
                              | (tg << 48);
        unsigned long long u2 = (unsigned long long)(unsigned short)hf[6]
                              | ((unsigned long long)(unsigned short)hf[7] << 16)
                              | (tg << 32) | (tg << 48);
        unsigned long long* dst = ring + (size_t)(t & (DEPTH-1))*SLOT_U64 + (w*64 + l)*3;
        st64(dst, u0); st64(dst+1, u1); st64(dst+2, u2);
        // no drain, no flag: tags self-validate; stores ack during next step
      }
      xa[0] = pack8(n0,n1); xa[1] = pack8(n2,n3);
      xa[2] = (lq < 2) ? pack8(n4,n5) : zf;
    }
  }
  else {
    // ================= stage B: layer 1 + head =================
    short* h0l = (short*)(smem + H0L_OFF);             // [2][16*HP]
    float* ypart = (float*)(smem + YP_OFF);            // [2][8][16]
    float* biassh = (float*)(smem + BS_OFF);
    float* woutsh = (float*)(smem + WO_OFF);
    for (int i = tid; i < 640; i += NTHR){
      const int ct = i >> 4, r = i & 15;
      const int row = (r&3)*HH + 4*ct + (r>>2);
      biassh[i] = bih1[row] + bhh1[row];
    }
    for (int i = tid; i < HH; i += NTHR) woutsh[i] = Wout[i];
    // Wih1 (25) + Whh1 kt0..2 (15) in regs; Whh1 kt3,4 (10) in LDS.
    s8b Wi[NTILE][5], Wh[NTILE][3];
    float woutv[NTILE];
    #pragma unroll
    for (int s = 0; s < NTILE; ++s){
      const int ct = w + 8*s;
      const int wrow = q*HH + 4*ct + h2;
      woutv[s] = Wout[4*ct + h2];
      #pragma unroll
      for (int kt = 0; kt < 5; ++kt)
        Wi[s][kt] = wfrag(Wih1 + (size_t)wrow*HH + kt*32 + lq*8);
      #pragma unroll
      for (int kt = 0; kt < 3; ++kt)
        Wh[s][kt] = wfrag(Whh1 + (size_t)wrow*HH + kt*32 + lq*8);
      #pragma unroll
      for (int kt = 3; kt < 5; ++kt)
        *(s8b*)(smem + ((w*10 + s*2 + (kt-3)) << 10) + (l << 4)) =
            wfrag(Whh1 + (size_t)wrow*HH + kt*32 + lq*8);
    }
    const float bo = bout[0];
    s8b h1a[5];
    #pragma unroll
    for (int kt = 0; kt < 5; ++kt) h1a[kt] = zf;
    float c1[NTILE] = {0.f,0.f,0.f,0.f,0.f};

    // prologue: spin-consume slot 0 -> h0l[0]; issue speculative loads slot 1
    unsigned long long in0 = 0, in1 = 0, in2 = 0;
    if (w < 5){
      const unsigned long long* src = ring + (w*64 + l)*3;
      in0 = ld64(src); in1 = ld64(src+1); in2 = ld64(src+2);
      bool ok = ((int)(in0>>48)==0) && ((int)(in1>>48)==0) && ((int)(in2>>48)==0);
      while (__ballot(ok) != ~0ull){
        __builtin_amdgcn_s_sleep(1);
        in0 = ld64(src); in1 = ld64(src+1); in2 = ld64(src+2);
        ok = ((int)(in0>>48)==0) && ((int)(in1>>48)==0) && ((int)(in2>>48)==0);
      }
      s8b v;
      v[0]=(short)in0; v[1]=(short)(in0>>16); v[2]=(short)(in0>>32);
      v[3]=(short)in1; v[4]=(short)(in1>>16); v[5]=(short)(in1>>32);
      v[6]=(short)in2; v[7]=(short)(in2>>16);
      *(s8b*)&h0l[lr*HP + w*32 + lq*8] = v;
      const unsigned long long* p1 = ring + (size_t)(1 & (DEPTH-1))*SLOT_U64 + (w*64 + l)*3;
      in0 = ld64(p1); in1 = ld64(p1+1); in2 = ld64(p1+2);
    }
    __syncthreads();

    for (int t = 0; t < TT; ++t){
      const short* h0b = h0l + (t&1)*16*HP;
      short* hb = hsh + (t&1)*16*HP;
      f4 acc[NTILE];
      #pragma unroll
      for (int s = 0; s < NTILE; ++s){
        const float b = biassh[(w + 8*s)*16 + lr];
        acc[s][0]=b; acc[s][1]=b; acc[s][2]=b; acc[s][3]=b;
        #pragma unroll
        for (int kt = 0; kt < 3; ++kt) acc[s] = mfma16(h1a[kt], Wh[s][kt], acc[s]);
        acc[s] = mfma16(h1a[3], *(const s8b*)(smem + ((w*10 + s*2 + 0) << 10) + (l << 4)), acc[s]);
        acc[s] = mfma16(h1a[4], *(const s8b*)(smem + ((w*10 + s*2 + 1) << 10) + (l << 4)), acc[s]);
      }
      s8b h0f[5];
      #pragma unroll
      for (int kt = 0; kt < 5; ++kt)
        h0f[kt] = *(const s8b*)&h0b[lr*HP + kt*32 + lq*8];
      #pragma unroll
      for (int s = 0; s < NTILE; ++s)
        #pragma unroll
        for (int kt = 0; kt < 5; ++kt) acc[s] = mfma16(h0f[kt], Wi[s][kt], acc[s]);

      float ysum = 0.f;
      #pragma unroll
      for (int s = 0; s < NTILE; ++s){
        float gv[4]; qtrans(acc[s], q, gv);
        const float cn = sigf(gv[1])*c1[s] + sigf(gv[0])*tanh_(gv[2]);
        c1[s] = cn;
        const float h = sigf(gv[3])*tanh_(cn);
        hb[(lq*4 + q)*HP + 4*(w + 8*s) + h2] = f2bf(h);
        ysum += h * woutv[s];
      }
      ysum += __shfl_xor(ysum, 4, 64);
      ysum += __shfl_xor(ysum, 8, 64);
      if ((l & 12) == 0) ypart[(t&1)*128 + w*16 + lq*4 + q] = ysum;

      // validate slot t+1 (loads issued last step), stage into h0l[(t+1)&1]
      if (w < 5 && t+1 < TT){
        const int tg = t+1;
        const unsigned long long* src =
            ring + (size_t)(tg & (DEPTH-1))*SLOT_U64 + (w*64 + l)*3;
        bool ok = ((int)(in0>>48)==tg) && ((int)(in1>>48)==tg) && ((int)(in2>>48)==tg);
        while (__ballot(ok) != ~0ull){
          __builtin_amdgcn_s_sleep(1);
          in0 = ld64(src); in1 = ld64(src+1); in2 = ld64(src+2);
          ok = ((int)(in0>>48)==tg) && ((int)(in1>>48)==tg) && ((int)(in2>>48)==tg);
        }
        s8b v;
        v[0]=(short)in0; v[1]=(short)(in0>>16); v[2]=(short)(in0>>32);
        v[3]=(short)in1; v[4]=(short)(in1>>16); v[5]=(short)(in1>>32);
        v[6]=(short)in2; v[7]=(short)(in2>>16);
        *(s8b*)&h0l[((t+1)&1)*16*HP + lr*HP + w*32 + lq*8] = v;
      }
      __syncthreads();                                 // h1(t), ypart, h0(t+1) visible
      #pragma unroll
      for (int kt = 0; kt < 5; ++kt)
        h1a[kt] = *(const s8b*)&hb[lr*HP + kt*32 + lq*8];
      if (w == 0 && l < 16){
        float s_ = bo;
        #pragma unroll
        for (int ww = 0; ww < NW; ++ww) s_ += ypart[(t&1)*128 + ww*16 + l];
        out[(size_t)(b0 + l)*TT + t] = fmaxf(s_, 0.f);
      }
      if (w < 5 && t+2 < TT){                          // speculative loads slot t+2
        const unsigned long long* p =
            ring + (size_t)((t+2) & (DEPTH-1))*SLOT_U64 + (w*64 + l)*3;
        in0 = ld64(p); in1 = ld64(p+1); in2 = ld64(p+2);
      }
      if (((t & 7) == 7) && tid == 0)                  // credit, post-barrier = free
        __hip_atomic_store(prog, t+1, __ATOMIC_RELEASE, __HIP_MEMORY_SCOPE_AGENT);
    }
  }
}

extern "C" void kernel_launch(void* const* d_in, const int* in_sizes, int n_in,
                              void* d_out, int out_size, void* d_ws, size_t ws_size,
                              hipStream_t stream)
{
  (void)in_sizes; (void)n_in; (void)out_size; (void)ws_size;
  (void)hipFuncSetAttribute(reinterpret_cast<const void*>(lstm2),
                            hipFuncAttributeMaxDynamicSharedMemorySize, SMEM_SZ);
  (void)hipMemsetAsync(d_ws, 0, 4096, stream);   // credit counters
  lstm2<<<dim3(NGRP*2), dim3(NTHR), SMEM_SZ, stream>>>(
      (const float*)d_in[0],
      (const float*)d_in[1], (const float*)d_in[2],
      (const float*)d_in[3], (const float*)d_in[4],
      (const float*)d_in[5], (const float*)d_in[6],
      (const float*)d_in[7], (const float*)d_in[8],
      (const float*)d_in[9], (const float*)d_in[10],
      (float*)d_out, (char*)d_ws);
}